// Round 4
// baseline (1804.613 us; speedup 1.0000x reference)
//
#include <hip/hip_runtime.h>
#include <hip/hip_bf16.h>
#include <stdint.h>

#define NU 100000
#define NI 50000
#define NB 1000
#define NN 151000      // total nodes
#define D  64
#define NE 10000000

typedef unsigned short u16;
typedef unsigned int   u32;

__device__ __forceinline__ float bf2f(u16 u) {
    union { u32 i; float f; } c; c.i = ((u32)u) << 16; return c.f;
}
__device__ __forceinline__ u16 f2bf(float f) {
    union { float f; u32 i; } c; c.f = f;
    // round-to-nearest-even bf16
    u32 lsb = (c.i >> 16) & 1;
    c.i += 0x7fffu + lsb;
    return (u16)(c.i >> 16);
}

// ---- CSR build ----
__global__ void k_hist(const int* __restrict__ rows, int* __restrict__ cnt) {
    int stride = gridDim.x * blockDim.x;
    for (int i = blockIdx.x * blockDim.x + threadIdx.x; i < NE; i += stride)
        atomicAdd(&cnt[rows[i]], 1);
}

__global__ void k_offsets(const int* __restrict__ cnt, int* __restrict__ off,
                          int* __restrict__ cur, int* __restrict__ gtotal) {
    __shared__ int sdata[256];
    __shared__ int sbase;
    int t = threadIdx.x;
    int gi = blockIdx.x * 256 + t;
    int c = (gi < NN) ? cnt[gi] : 0;
    int x = c;
    sdata[t] = x;
    __syncthreads();
    for (int ofs = 1; ofs < 256; ofs <<= 1) {
        int y = (t >= ofs) ? sdata[t - ofs] : 0;
        __syncthreads();
        x += y;
        sdata[t] = x;
        __syncthreads();
    }
    if (t == 255) sbase = atomicAdd(gtotal, x);
    __syncthreads();
    if (gi < NN) {
        // exclusive prefix within block + atomically-reserved global base.
        // (off[] is not globally monotone across blocks — fine: segments are
        //  disjoint and each row's extent is [off[r], off[r]+cnt[r]).)
        int o = sbase + x - c;
        off[gi] = o;
        cur[gi] = o;
    }
}

__global__ void k_scatter(const int* __restrict__ rows, const int* __restrict__ cols,
                          const float* __restrict__ vals, int* __restrict__ cur,
                          int* __restrict__ ci, float* __restrict__ cv) {
    int stride = gridDim.x * blockDim.x;
    for (int i = blockIdx.x * blockDim.x + threadIdx.x; i < NE; i += stride) {
        int r = rows[i];
        int p = atomicAdd(&cur[r], 1);
        ci[p] = cols[i];
        cv[p] = vals[i];
    }
}

// ---- x0 = concat(embeddings) -> bf16 xa; acc = fp32 copy ----
__global__ void k_init(const float4* __restrict__ ue, const float4* __restrict__ ie,
                       const float4* __restrict__ be, ushort4* __restrict__ xa,
                       float4* __restrict__ acc) {
    int i4 = blockIdx.x * blockDim.x + threadIdx.x;   // unit of 4 floats
    if (i4 >= NN * D / 4) return;
    float4 v;
    if (i4 < NU * D / 4)             v = ue[i4];
    else if (i4 < (NU + NI) * D / 4) v = ie[i4 - NU * D / 4];
    else                             v = be[i4 - (NU + NI) * D / 4];
    acc[i4] = v;
    ushort4 h;
    h.x = f2bf(v.x); h.y = f2bf(v.y); h.z = f2bf(v.z); h.w = f2bf(v.w);
    xa[i4] = h;
}

// ---- SpMM: one 64-lane wave per row, lane = dim ----
template<int LAST>
__global__ __launch_bounds__(256) void k_spmm(
    const int* __restrict__ off, const int* __restrict__ cnt,
    const int* __restrict__ ci, const float* __restrict__ cv,
    const u16* __restrict__ xin, u16* __restrict__ xout,
    float* __restrict__ acc, float* __restrict__ out) {
    int gid  = blockIdx.x * blockDim.x + threadIdx.x;
    int row  = gid >> 6;
    int lane = threadIdx.x & 63;
    if (row >= NN) return;
    int base = __builtin_amdgcn_readfirstlane(off[row]);
    int deg  = __builtin_amdgcn_readfirstlane(cnt[row]);
    float s0 = 0.f, s1 = 0.f, s2 = 0.f, s3 = 0.f;
    int e = 0;
    for (; e + 4 <= deg; e += 4) {
        int c0 = ci[base + e];
        int c1 = ci[base + e + 1];
        int c2 = ci[base + e + 2];
        int c3 = ci[base + e + 3];
        float v0 = cv[base + e];
        float v1 = cv[base + e + 1];
        float v2 = cv[base + e + 2];
        float v3 = cv[base + e + 3];
        s0 += v0 * bf2f(xin[c0 * D + lane]);
        s1 += v1 * bf2f(xin[c1 * D + lane]);
        s2 += v2 * bf2f(xin[c2 * D + lane]);
        s3 += v3 * bf2f(xin[c3 * D + lane]);
    }
    for (; e < deg; ++e) {
        int c0 = ci[base + e];
        s0 += cv[base + e] * bf2f(xin[c0 * D + lane]);
    }
    float s = (s0 + s1) + (s2 + s3);
    int o = row * D + lane;
    if (LAST) {
        out[o] = (acc[o] + s) * 0.25f;
    } else {
        acc[o] += s;
        xout[o] = f2bf(s);
    }
}

extern "C" void kernel_launch(void* const* d_in, const int* in_sizes, int n_in,
                              void* d_out, int out_size, void* d_ws, size_t ws_size,
                              hipStream_t stream) {
    const int*   rows = (const int*)d_in[0];
    const int*   cols = (const int*)d_in[1];
    const float* vals = (const float*)d_in[2];
    float* out = (float*)d_out;

    char* w = (char*)d_ws;
    size_t p = 0;
#define WALLOC(var, type, count) \
    type* var = (type*)(w + p); p += (((size_t)(count) * sizeof(type)) + 255) & ~(size_t)255;
    WALLOC(cnt,    int, NN)
    WALLOC(off,    int, NN)
    WALLOC(cur,    int, NN)
    WALLOC(gtotal, int, 64)
    WALLOC(ci,     int,   (size_t)NE)
    WALLOC(cv,     float, (size_t)NE)
    WALLOC(xa,     u16,   (size_t)NN * D)
    WALLOC(xb,     u16,   (size_t)NN * D)
    WALLOC(acc,    float, (size_t)NN * D)
#undef WALLOC
    (void)p; (void)ws_size; (void)in_sizes; (void)n_in; (void)out_size;

    hipMemsetAsync(cnt, 0, (size_t)NN * sizeof(int), stream);
    hipMemsetAsync(gtotal, 0, sizeof(int), stream);

    k_hist<<<2048, 256, 0, stream>>>(rows, cnt);
    k_offsets<<<(NN + 255) / 256, 256, 0, stream>>>(cnt, off, cur, gtotal);
    k_scatter<<<2048, 256, 0, stream>>>(rows, cols, vals, cur, ci, cv);
    k_init<<<(NN * D / 4 + 255) / 256, 256, 0, stream>>>(
        (const float4*)d_in[3], (const float4*)d_in[4],
        (const float4*)d_in[5], (ushort4*)xa, (float4*)acc);

    int spmm_blocks = NN / 4;   // 4 waves (rows) per 256-thread block; NN%4==0
    // layer 1: xa -> xb
    k_spmm<0><<<spmm_blocks, 256, 0, stream>>>(off, cnt, ci, cv, xa, xb, acc, out);
    // layer 2: xb -> xa
    k_spmm<0><<<spmm_blocks, 256, 0, stream>>>(off, cnt, ci, cv, xb, xa, acc, out);
    // layer 3: xa -> final output (= (acc + y3)/4)
    k_spmm<1><<<spmm_blocks, 256, 0, stream>>>(off, cnt, ci, cv, xa, xb, acc, out);

    // echo user_emb / item_emb (fp32)
    hipMemcpyAsync(out + (size_t)NN * D, d_in[3], (size_t)NU * D * sizeof(float),
                   hipMemcpyDeviceToDevice, stream);
    hipMemcpyAsync(out + (size_t)NN * D + (size_t)NU * D, d_in[4],
                   (size_t)NI * D * sizeof(float), hipMemcpyDeviceToDevice, stream);
}

// Round 5
// 1622.393 us; speedup vs baseline: 1.1123x; 1.1123x over previous
//
#include <hip/hip_runtime.h>
#include <hip/hip_bf16.h>
#include <stdint.h>

#define NU 100000
#define NI 50000
#define NB 1000
#define NN 151000      // total nodes
#define D  64
#define NE 10000000

typedef unsigned short u16;
typedef unsigned int   u32;

__device__ __forceinline__ float bf2f(u16 u) {
    union { u32 i; float f; } c; c.i = ((u32)u) << 16; return c.f;
}
__device__ __forceinline__ u16 f2bf(float f) {
    union { float f; u32 i; } c; c.f = f;
    u32 lsb = (c.i >> 16) & 1;          // round-to-nearest-even bf16
    c.i += 0x7fffu + lsb;
    return (u16)(c.i >> 16);
}

// ---- CSR build ----
__global__ void k_hist(const int* __restrict__ rows, int* __restrict__ cnt) {
    int stride = gridDim.x * blockDim.x;
    for (int i = blockIdx.x * blockDim.x + threadIdx.x; i < NE; i += stride)
        atomicAdd(&cnt[rows[i]], 1);
}

__global__ void k_offsets(const int* __restrict__ cnt, int* __restrict__ off,
                          int* __restrict__ cur, int* __restrict__ gtotal) {
    __shared__ int sdata[256];
    __shared__ int sbase;
    int t = threadIdx.x;
    int gi = blockIdx.x * 256 + t;
    int c = (gi < NN) ? cnt[gi] : 0;
    int x = c;
    sdata[t] = x;
    __syncthreads();
    for (int ofs = 1; ofs < 256; ofs <<= 1) {
        int y = (t >= ofs) ? sdata[t - ofs] : 0;
        __syncthreads();
        x += y;
        sdata[t] = x;
        __syncthreads();
    }
    if (t == 255) sbase = atomicAdd(gtotal, x);
    __syncthreads();
    if (gi < NN) {
        // exclusive prefix within block + atomically-reserved global base.
        // off[] not globally monotone across blocks — fine: segments disjoint.
        int o = sbase + x - c;
        off[gi] = o;
        cur[gi] = o;
    }
}

// one random 8B store per edge (was 2x 4B to two arrays -> half the dirty lines)
__global__ void k_scatter(const int* __restrict__ rows, const int* __restrict__ cols,
                          const float* __restrict__ vals, int* __restrict__ cur,
                          int2* __restrict__ cicv) {
    int stride = gridDim.x * blockDim.x;
    for (int i = blockIdx.x * blockDim.x + threadIdx.x; i < NE; i += stride) {
        int r = rows[i];
        int p = atomicAdd(&cur[r], 1);
        cicv[p] = make_int2(cols[i], __float_as_int(vals[i]));
    }
}

// ---- x0 = concat(embeddings) -> bf16 xa; acc = fp32 copy ----
__global__ void k_init(const float4* __restrict__ ue, const float4* __restrict__ ie,
                       const float4* __restrict__ be, ushort4* __restrict__ xa,
                       float4* __restrict__ acc) {
    int i4 = blockIdx.x * blockDim.x + threadIdx.x;   // unit of 4 floats
    if (i4 >= NN * D / 4) return;
    float4 v;
    if (i4 < NU * D / 4)             v = ue[i4];
    else if (i4 < (NU + NI) * D / 4) v = ie[i4 - NU * D / 4];
    else                             v = be[i4 - (NU + NI) * D / 4];
    acc[i4] = v;
    ushort4 h;
    h.x = f2bf(v.x); h.y = f2bf(v.y); h.z = f2bf(v.z); h.w = f2bf(v.w);
    xa[i4] = h;
}

// ---- SpMM: one wave per row; 4 edges in flight per gather instr.
// lane = (g,p): g=lane>>4 edge slot 0..3, p=lane&15 dim-quad (dims 4p..4p+3).
template<int LAST>
__global__ __launch_bounds__(256) void k_spmm(
    const int* __restrict__ off, const int* __restrict__ cnt,
    const int2* __restrict__ cicv,
    const u16* __restrict__ xin, ushort4* __restrict__ xout,
    float4* __restrict__ acc, float4* __restrict__ out) {
    int gid  = blockIdx.x * blockDim.x + threadIdx.x;
    int row  = gid >> 6;
    int lane = threadIdx.x & 63;
    if (row >= NN) return;
    int base = __builtin_amdgcn_readfirstlane(off[row]);
    int deg  = __builtin_amdgcn_readfirstlane(cnt[row]);
    int g = lane >> 4;
    int p = lane & 15;
    float s0 = 0.f, s1 = 0.f, s2 = 0.f, s3 = 0.f;
    for (int e = 0; e < deg; e += 8) {
        int2 ra = cicv[base + e + g];       // 16-lane broadcast, 4 addrs/wave
        int2 rb = cicv[base + e + 4 + g];
        bool oka = (e + g) < deg;
        bool okb = (e + 4 + g) < deg;
        int   ca = oka ? ra.x : 0;
        float fa = oka ? __int_as_float(ra.y) : 0.f;
        int   cb = okb ? rb.x : 0;
        float fb = okb ? __int_as_float(rb.y) : 0.f;
        ushort4 ha = *(const ushort4*)(xin + (size_t)ca * D + p * 4);
        ushort4 hb = *(const ushort4*)(xin + (size_t)cb * D + p * 4);
        s0 += fa * bf2f(ha.x); s1 += fa * bf2f(ha.y);
        s2 += fa * bf2f(ha.z); s3 += fa * bf2f(ha.w);
        s0 += fb * bf2f(hb.x); s1 += fb * bf2f(hb.y);
        s2 += fb * bf2f(hb.z); s3 += fb * bf2f(hb.w);
    }
    // reduce across the 4 edge-slot groups (xor 16 then 32)
    s0 += __shfl_xor(s0, 16); s0 += __shfl_xor(s0, 32);
    s1 += __shfl_xor(s1, 16); s1 += __shfl_xor(s1, 32);
    s2 += __shfl_xor(s2, 16); s2 += __shfl_xor(s2, 32);
    s3 += __shfl_xor(s3, 16); s3 += __shfl_xor(s3, 32);
    int o4 = row * 16 + p;                  // float4 / ushort4 index
    if (LAST) {
        if (g == 0) {
            float4 a = acc[o4];
            out[o4] = make_float4((a.x + s0) * 0.25f, (a.y + s1) * 0.25f,
                                  (a.z + s2) * 0.25f, (a.w + s3) * 0.25f);
        }
    } else {
        if (g == 0) {
            float4 a = acc[o4];
            acc[o4] = make_float4(a.x + s0, a.y + s1, a.z + s2, a.w + s3);
        } else if (g == 1) {
            ushort4 h;
            h.x = f2bf(s0); h.y = f2bf(s1); h.z = f2bf(s2); h.w = f2bf(s3);
            xout[o4] = h;
        }
    }
}

extern "C" void kernel_launch(void* const* d_in, const int* in_sizes, int n_in,
                              void* d_out, int out_size, void* d_ws, size_t ws_size,
                              hipStream_t stream) {
    const int*   rows = (const int*)d_in[0];
    const int*   cols = (const int*)d_in[1];
    const float* vals = (const float*)d_in[2];
    float* out = (float*)d_out;

    char* w = (char*)d_ws;
    size_t p = 0;
#define WALLOC(var, type, count) \
    type* var = (type*)(w + p); p += (((size_t)(count) * sizeof(type)) + 255) & ~(size_t)255;
    WALLOC(cnt,    int, NN)
    WALLOC(off,    int, NN)
    WALLOC(cur,    int, NN)
    WALLOC(gtotal, int, 64)
    WALLOC(cicv,   int2,  (size_t)NE + 8)   // +8 pad: spmm tail reads (clamped)
    WALLOC(xa,     u16,   (size_t)NN * D)
    WALLOC(xb,     u16,   (size_t)NN * D)
    WALLOC(acc,    float, (size_t)NN * D)
#undef WALLOC
    (void)p; (void)ws_size; (void)in_sizes; (void)n_in; (void)out_size;

    hipMemsetAsync(cnt, 0, (size_t)NN * sizeof(int), stream);
    hipMemsetAsync(gtotal, 0, sizeof(int), stream);

    k_hist<<<2048, 256, 0, stream>>>(rows, cnt);
    k_offsets<<<(NN + 255) / 256, 256, 0, stream>>>(cnt, off, cur, gtotal);
    k_scatter<<<2048, 256, 0, stream>>>(rows, cols, vals, cur, cicv);
    k_init<<<(NN * D / 4 + 255) / 256, 256, 0, stream>>>(
        (const float4*)d_in[3], (const float4*)d_in[4],
        (const float4*)d_in[5], (ushort4*)xa, (float4*)acc);

    int spmm_blocks = NN / 4;   // 4 waves (rows) per 256-thread block; NN%4==0
    k_spmm<0><<<spmm_blocks, 256, 0, stream>>>(off, cnt, cicv, xa, (ushort4*)xb,
                                               (float4*)acc, (float4*)out);
    k_spmm<0><<<spmm_blocks, 256, 0, stream>>>(off, cnt, cicv, xb, (ushort4*)xa,
                                               (float4*)acc, (float4*)out);
    k_spmm<1><<<spmm_blocks, 256, 0, stream>>>(off, cnt, cicv, xa, (ushort4*)xb,
                                               (float4*)acc, (float4*)out);

    // echo user_emb / item_emb (fp32)
    hipMemcpyAsync(out + (size_t)NN * D, d_in[3], (size_t)NU * D * sizeof(float),
                   hipMemcpyDeviceToDevice, stream);
    hipMemcpyAsync(out + (size_t)NN * D + (size_t)NU * D, d_in[4],
                   (size_t)NI * D * sizeof(float), hipMemcpyDeviceToDevice, stream);
}

// Round 6
// 1287.144 us; speedup vs baseline: 1.4020x; 1.2605x over previous
//
#include <hip/hip_runtime.h>
#include <hip/hip_bf16.h>
#include <stdint.h>

#define NU 100000
#define NI 50000
#define NB 1000
#define NN 151000      // total nodes
#define D  64
#define NE 10000000

#define BSH   6                   // 64 rows per bucket
#define BROWS 64
#define NBUCK 2360                // ceil(NN / 64)
#define SPLIT 8                   // XCD-local append streams per bucket
#define NSUB  (NBUCK * SPLIT)     // 18880
#define CAP   704                 // per-substream capacity (mean 530, +7.5 sigma)

typedef unsigned short u16;
typedef unsigned int   u32;

__device__ __forceinline__ float bf2f(u16 u) {
    union { u32 i; float f; } c; c.i = ((u32)u) << 16; return c.f;
}
__device__ __forceinline__ u16 f2bf(float f) {
    union { float f; u32 i; } c; c.f = f;
    u32 lsb = (c.i >> 16) & 1;          // round-to-nearest-even bf16
    c.i += 0x7fffu + lsb;
    return (u16)(c.i >> 16);
}

// ---- phase 1: bin edges into XCD-local append streams (sequential tails) ----
__global__ void k_bin(const int* __restrict__ rows, const int* __restrict__ cols,
                      const float* __restrict__ vals,
                      int* __restrict__ subcur, int2* __restrict__ subbuf) {
    int stride = gridDim.x * blockDim.x;
    int s = blockIdx.x & (SPLIT - 1);   // same split ~ same XCD (round-robin heuristic)
    for (int i = blockIdx.x * blockDim.x + threadIdx.x; i < NE; i += stride) {
        int r = rows[i];
        int sub = ((r >> BSH) << 3) + s;
        int pos = atomicAdd(&subcur[sub], 1);
        if (pos < CAP)
            subbuf[(size_t)sub * CAP + pos] =
                make_int2(((r & (BROWS - 1)) << 18) | cols[i], __float_as_int(vals[i]));
    }
}

// ---- phase 2: per-bucket CSR build entirely in LDS; sequential global writes ----
__global__ __launch_bounds__(256) void k_csr(
    const int* __restrict__ subcur, const int2* __restrict__ subbuf,
    int* __restrict__ off, int* __restrict__ cnt, int* __restrict__ gtotal,
    int2* __restrict__ cicv) {
    __shared__ int slen[SPLIT];
    __shared__ int rcnt[BROWS], rexc[BROWS], lcur[BROWS];
    __shared__ int sbase, stot;
    __shared__ int2 sbuf[SPLIT * CAP];   // 5632 * 8B = 45KB; T <= SPLIT*CAP always
    int b = blockIdx.x;
    int tid = threadIdx.x;
    if (tid < SPLIT) {
        int l = subcur[b * SPLIT + tid];
        slen[tid] = l > CAP ? CAP : l;
    }
    if (tid < BROWS) rcnt[tid] = 0;
    __syncthreads();
    if (tid == 0) {
        int a = 0;
        for (int s = 0; s < SPLIT; ++s) a += slen[s];
        stot = a;
    }
    __syncthreads();
    int T = stot;
    // pass 1: per-row histogram
    for (int s = 0; s < SPLIT; ++s) {
        const int2* src = subbuf + (size_t)(b * SPLIT + s) * CAP;
        int l = slen[s];
        for (int j = tid; j < l; j += 256)
            atomicAdd(&rcnt[(u32)src[j].x >> 18], 1);
    }
    __syncthreads();
    // exclusive prefix over the 64 row-counters (wave 0)
    if (tid < 64) {
        int v = rcnt[tid];
        int x = v;
        for (int d = 1; d < 64; d <<= 1) {
            int t = __shfl_up(x, d);
            if (tid >= d) x += t;
        }
        rexc[tid] = x - v;
        if (tid == 63) sbase = atomicAdd(gtotal, x);   // order-free disjoint segments
    }
    __syncthreads();
    int base = sbase;
    if (tid < BROWS) {
        int r = b * BROWS + tid;
        if (r < NN) { off[r] = base + rexc[tid]; cnt[r] = rcnt[tid]; }
        lcur[tid] = rexc[tid];
    }
    __syncthreads();
    // pass 2: scatter into LDS in CSR order (random stores stay in LDS)
    for (int s = 0; s < SPLIT; ++s) {
        const int2* src = subbuf + (size_t)(b * SPLIT + s) * CAP;
        int l = slen[s];
        for (int j = tid; j < l; j += 256) {
            int2 rec = src[j];
            int rl = (u32)rec.x >> 18;
            int dst = atomicAdd(&lcur[rl], 1);
            sbuf[dst] = make_int2(rec.x & 0x3FFFF, rec.y);
        }
    }
    __syncthreads();
    // dump: purely sequential coalesced stores
    for (int j = tid; j < T; j += 256)
        cicv[base + j] = sbuf[j];
}

// ---- x0 = concat(embeddings) -> bf16 xa; acc = fp32 copy ----
__global__ void k_init(const float4* __restrict__ ue, const float4* __restrict__ ie,
                       const float4* __restrict__ be, ushort4* __restrict__ xa,
                       float4* __restrict__ acc) {
    int i4 = blockIdx.x * blockDim.x + threadIdx.x;   // unit of 4 floats
    if (i4 >= NN * D / 4) return;
    float4 v;
    if (i4 < NU * D / 4)             v = ue[i4];
    else if (i4 < (NU + NI) * D / 4) v = ie[i4 - NU * D / 4];
    else                             v = be[i4 - (NU + NI) * D / 4];
    acc[i4] = v;
    ushort4 h;
    h.x = f2bf(v.x); h.y = f2bf(v.y); h.z = f2bf(v.z); h.w = f2bf(v.w);
    xa[i4] = h;
}

// ---- SpMM: one wave per row; 4 edges in flight per gather instr (unchanged) ----
template<int LAST>
__global__ __launch_bounds__(256) void k_spmm(
    const int* __restrict__ off, const int* __restrict__ cnt,
    const int2* __restrict__ cicv,
    const u16* __restrict__ xin, ushort4* __restrict__ xout,
    float4* __restrict__ acc, float4* __restrict__ out) {
    int gid  = blockIdx.x * blockDim.x + threadIdx.x;
    int row  = gid >> 6;
    int lane = threadIdx.x & 63;
    if (row >= NN) return;
    int base = __builtin_amdgcn_readfirstlane(off[row]);
    int deg  = __builtin_amdgcn_readfirstlane(cnt[row]);
    int g = lane >> 4;
    int p = lane & 15;
    float s0 = 0.f, s1 = 0.f, s2 = 0.f, s3 = 0.f;
    for (int e = 0; e < deg; e += 8) {
        int2 ra = cicv[base + e + g];       // 16-lane broadcast, 4 addrs/wave
        int2 rb = cicv[base + e + 4 + g];
        bool oka = (e + g) < deg;
        bool okb = (e + 4 + g) < deg;
        int   ca = oka ? ra.x : 0;
        float fa = oka ? __int_as_float(ra.y) : 0.f;
        int   cb = okb ? rb.x : 0;
        float fb = okb ? __int_as_float(rb.y) : 0.f;
        ushort4 ha = *(const ushort4*)(xin + (size_t)ca * D + p * 4);
        ushort4 hb = *(const ushort4*)(xin + (size_t)cb * D + p * 4);
        s0 += fa * bf2f(ha.x); s1 += fa * bf2f(ha.y);
        s2 += fa * bf2f(ha.z); s3 += fa * bf2f(ha.w);
        s0 += fb * bf2f(hb.x); s1 += fb * bf2f(hb.y);
        s2 += fb * bf2f(hb.z); s3 += fb * bf2f(hb.w);
    }
    s0 += __shfl_xor(s0, 16); s0 += __shfl_xor(s0, 32);
    s1 += __shfl_xor(s1, 16); s1 += __shfl_xor(s1, 32);
    s2 += __shfl_xor(s2, 16); s2 += __shfl_xor(s2, 32);
    s3 += __shfl_xor(s3, 16); s3 += __shfl_xor(s3, 32);
    int o4 = row * 16 + p;                  // float4 / ushort4 index
    if (LAST) {
        if (g == 0) {
            float4 a = acc[o4];
            out[o4] = make_float4((a.x + s0) * 0.25f, (a.y + s1) * 0.25f,
                                  (a.z + s2) * 0.25f, (a.w + s3) * 0.25f);
        }
    } else {
        if (g == 0) {
            float4 a = acc[o4];
            acc[o4] = make_float4(a.x + s0, a.y + s1, a.z + s2, a.w + s3);
        } else if (g == 1) {
            ushort4 h;
            h.x = f2bf(s0); h.y = f2bf(s1); h.z = f2bf(s2); h.w = f2bf(s3);
            xout[o4] = h;
        }
    }
}

extern "C" void kernel_launch(void* const* d_in, const int* in_sizes, int n_in,
                              void* d_out, int out_size, void* d_ws, size_t ws_size,
                              hipStream_t stream) {
    const int*   rows = (const int*)d_in[0];
    const int*   cols = (const int*)d_in[1];
    const float* vals = (const float*)d_in[2];
    float* out = (float*)d_out;

    char* w = (char*)d_ws;
    size_t p = 0;
#define WALLOC(var, type, count) \
    type* var = (type*)(w + p); p += (((size_t)(count) * sizeof(type)) + 255) & ~(size_t)255;
    WALLOC(subcur, int, NSUB)
    WALLOC(gtotal, int, 64)
    WALLOC(off,    int, NN)
    WALLOC(cnt,    int, NN)
    // overlay region: subbuf is dead after k_csr; xa/xb/acc reuse its space
    size_t regA = p;
    int2* subbuf = (int2*)(w + regA);               // 18880*704*8 = 106.3 MB
    size_t subbuf_sz = ((size_t)NSUB * CAP * sizeof(int2) + 255) & ~(size_t)255;
    u16*   xa = (u16*)(w + regA);                   // 19.3 MB
    u16*   xb = (u16*)(w + regA + (size_t)NN * D * sizeof(u16));
    float* acc = (float*)(w + regA + 2 * (size_t)NN * D * sizeof(u16));  // 38.6 MB
    p = regA + subbuf_sz;
    WALLOC(cicv, int2, (size_t)NE + 8)              // +8 pad: spmm tail (clamped)
#undef WALLOC
    (void)p; (void)ws_size; (void)in_sizes; (void)n_in; (void)out_size;

    hipMemsetAsync(subcur, 0, (size_t)NSUB * sizeof(int), stream);
    hipMemsetAsync(gtotal, 0, sizeof(int), stream);

    k_bin<<<2048, 256, 0, stream>>>(rows, cols, vals, subcur, subbuf);
    k_csr<<<NBUCK, 256, 0, stream>>>(subcur, subbuf, off, cnt, gtotal, cicv);
    k_init<<<(NN * D / 4 + 255) / 256, 256, 0, stream>>>(
        (const float4*)d_in[3], (const float4*)d_in[4],
        (const float4*)d_in[5], (ushort4*)xa, (float4*)acc);

    int spmm_blocks = NN / 4;   // 4 waves (rows) per 256-thread block; NN%4==0
    k_spmm<0><<<spmm_blocks, 256, 0, stream>>>(off, cnt, cicv, xa, (ushort4*)xb,
                                               (float4*)acc, (float4*)out);
    k_spmm<0><<<spmm_blocks, 256, 0, stream>>>(off, cnt, cicv, xb, (ushort4*)xa,
                                               (float4*)acc, (float4*)out);
    k_spmm<1><<<spmm_blocks, 256, 0, stream>>>(off, cnt, cicv, xa, (ushort4*)xb,
                                               (float4*)acc, (float4*)out);

    // echo user_emb / item_emb (fp32)
    hipMemcpyAsync(out + (size_t)NN * D, d_in[3], (size_t)NU * D * sizeof(float),
                   hipMemcpyDeviceToDevice, stream);
    hipMemcpyAsync(out + (size_t)NN * D + (size_t)NU * D, d_in[4],
                   (size_t)NI * D * sizeof(float), hipMemcpyDeviceToDevice, stream);
}

// Round 8
// 998.218 us; speedup vs baseline: 1.8078x; 1.2894x over previous
//
#include <hip/hip_runtime.h>
#include <hip/hip_bf16.h>
#include <stdint.h>

#define NU 100000
#define NI 50000
#define NB 1000
#define NN 151000      // total nodes
#define D  64
#define NE 10000000

#define BSH   6                   // 64 rows per bucket
#define BROWS 64
#define NBUCK 2360                // ceil(NN / 64)
#define CAPB  5632                // bucket capacity (mean 4238, sigma ~65 -> +21 sigma)
#define BINB  256                 // k_bin blocks
#define BINT  512                 // k_bin threads per block

typedef unsigned short u16;
typedef unsigned int   u32;

__device__ __forceinline__ float bf2f(u16 u) {
    union { u32 i; float f; } c; c.i = ((u32)u) << 16; return c.f;
}
__device__ __forceinline__ u16 f2bf(float f) {
    union { float f; u32 i; } c; c.f = f;
    u32 lsb = (c.i >> 16) & 1;          // round-to-nearest-even bf16
    c.i += 0x7fffu + lsb;
    return (u16)(c.i >> 16);
}

// ---- phase 1: block-local counting sort into bucket regions.
// One global atomic per (block,bucket); stores are contiguous runs (~16 recs).
__global__ __launch_bounds__(BINT) void k_bin(
    const int* __restrict__ rows, const int* __restrict__ cols,
    const float* __restrict__ vals,
    int* __restrict__ bucketcur, int2* __restrict__ subbuf) {
    __shared__ int hcnt[NBUCK];   // 9.4 KB
    __shared__ int hcur[NBUCK];   // 9.4 KB
    int b = blockIdx.x, tid = threadIdx.x;
    long e0 = (long)b * NE / BINB;
    long e1 = (long)(b + 1) * NE / BINB;
    for (int j = tid; j < NBUCK; j += BINT) hcnt[j] = 0;
    __syncthreads();
    for (long i = e0 + tid; i < e1; i += BINT)
        atomicAdd(&hcnt[rows[i] >> BSH], 1);            // LDS atomic
    __syncthreads();
    for (int j = tid; j < NBUCK; j += BINT) {
        int c = hcnt[j];
        hcur[j] = c ? atomicAdd(&bucketcur[j], c) : 0;  // chunk reservation
    }
    __syncthreads();
    for (long i = e0 + tid; i < e1; i += BINT) {
        int r  = rows[i];
        int bk = r >> BSH;
        int pos = atomicAdd(&hcur[bk], 1);              // LDS atomic
        if (pos < CAPB)
            subbuf[(size_t)bk * CAPB + pos] =
                make_int2(((r & (BROWS - 1)) << 18) | cols[i], __float_as_int(vals[i]));
    }
}

// ---- phase 2: per-bucket CSR build entirely in LDS; sequential global writes ----
__global__ __launch_bounds__(256) void k_csr(
    const int* __restrict__ bucketcur, const int2* __restrict__ subbuf,
    int* __restrict__ off, int* __restrict__ cnt, int* __restrict__ gtotal,
    int2* __restrict__ cicv) {
    __shared__ int rcnt[BROWS], rexc[BROWS], lcur[BROWS];
    __shared__ int sbase;
    __shared__ int2 sbuf[CAPB];   // 45 KB
    int b = blockIdx.x, tid = threadIdx.x;
    int T = bucketcur[b]; if (T > CAPB) T = CAPB;
    if (tid < BROWS) rcnt[tid] = 0;
    __syncthreads();
    const int2* src = subbuf + (size_t)b * CAPB;
    for (int j = tid; j < T; j += 256)
        atomicAdd(&rcnt[(u32)src[j].x >> 18], 1);
    __syncthreads();
    if (tid < 64) {
        int v = rcnt[tid], x = v;
        for (int d = 1; d < 64; d <<= 1) {
            int t = __shfl_up(x, d);
            if (tid >= d) x += t;
        }
        rexc[tid] = x - v;
        if (tid == 63) sbase = atomicAdd(gtotal, x);   // disjoint segments, order-free
    }
    __syncthreads();
    int base = sbase;
    if (tid < BROWS) {
        int r = b * BROWS + tid;
        if (r < NN) { off[r] = base + rexc[tid]; cnt[r] = rcnt[tid]; }
        lcur[tid] = rexc[tid];
    }
    __syncthreads();
    for (int j = tid; j < T; j += 256) {
        int2 rec = src[j];
        int rl = (u32)rec.x >> 18;
        int dst = atomicAdd(&lcur[rl], 1);
        sbuf[dst] = make_int2(rec.x & 0x3FFFF, rec.y);
    }
    __syncthreads();
    for (int j = tid; j < T; j += 256)     // purely sequential coalesced stores
        cicv[base + j] = sbuf[j];
}

// ---- x0 = concat(embeddings) -> bf16 xa; acc = fp32 copy ----
__global__ void k_init(const float4* __restrict__ ue, const float4* __restrict__ ie,
                       const float4* __restrict__ be, ushort4* __restrict__ xa,
                       float4* __restrict__ acc) {
    int i4 = blockIdx.x * blockDim.x + threadIdx.x;   // unit of 4 floats
    if (i4 >= NN * D / 4) return;
    float4 v;
    if (i4 < NU * D / 4)             v = ue[i4];
    else if (i4 < (NU + NI) * D / 4) v = ie[i4 - NU * D / 4];
    else                             v = be[i4 - (NU + NI) * D / 4];
    acc[i4] = v;
    ushort4 h;
    h.x = f2bf(v.x); h.y = f2bf(v.y); h.z = f2bf(v.z); h.w = f2bf(v.w);
    xa[i4] = h;
}

// ---- SpMM: one wave per row; 16 edges/iter, 4 gathers in flight ----
template<int LAST>
__global__ __launch_bounds__(256) void k_spmm(
    const int* __restrict__ off, const int* __restrict__ cnt,
    const int2* __restrict__ cicv,
    const u16* __restrict__ xin, ushort4* __restrict__ xout,
    float4* __restrict__ acc, float4* __restrict__ out) {
    int gid  = blockIdx.x * blockDim.x + threadIdx.x;
    int row  = gid >> 6;
    int lane = threadIdx.x & 63;
    if (row >= NN) return;
    int base = __builtin_amdgcn_readfirstlane(off[row]);
    int deg  = __builtin_amdgcn_readfirstlane(cnt[row]);
    int g = lane >> 4;
    int p = lane & 15;
    float s0 = 0.f, s1 = 0.f, s2 = 0.f, s3 = 0.f;
    for (int e = 0; e < deg; e += 16) {
        int2 ra = cicv[base + e + g];
        int2 rb = cicv[base + e + 4 + g];
        int2 rc = cicv[base + e + 8 + g];
        int2 rd = cicv[base + e + 12 + g];
        bool oka = (e + g)      < deg;
        bool okb = (e + 4 + g)  < deg;
        bool okc = (e + 8 + g)  < deg;
        bool okd = (e + 12 + g) < deg;
        int   ca = oka ? ra.x : 0;  float fa = oka ? __int_as_float(ra.y) : 0.f;
        int   cb = okb ? rb.x : 0;  float fb = okb ? __int_as_float(rb.y) : 0.f;
        int   cc = okc ? rc.x : 0;  float fc = okc ? __int_as_float(rc.y) : 0.f;
        int   cd = okd ? rd.x : 0;  float fd = okd ? __int_as_float(rd.y) : 0.f;
        ushort4 ha = *(const ushort4*)(xin + (size_t)ca * D + p * 4);
        ushort4 hb = *(const ushort4*)(xin + (size_t)cb * D + p * 4);
        ushort4 hc = *(const ushort4*)(xin + (size_t)cc * D + p * 4);
        ushort4 hd = *(const ushort4*)(xin + (size_t)cd * D + p * 4);
        s0 += fa * bf2f(ha.x); s1 += fa * bf2f(ha.y);
        s2 += fa * bf2f(ha.z); s3 += fa * bf2f(ha.w);
        s0 += fb * bf2f(hb.x); s1 += fb * bf2f(hb.y);
        s2 += fb * bf2f(hb.z); s3 += fb * bf2f(hb.w);
        s0 += fc * bf2f(hc.x); s1 += fc * bf2f(hc.y);
        s2 += fc * bf2f(hc.z); s3 += fc * bf2f(hc.w);
        s0 += fd * bf2f(hd.x); s1 += fd * bf2f(hd.y);
        s2 += fd * bf2f(hd.z); s3 += fd * bf2f(hd.w);
    }
    s0 += __shfl_xor(s0, 16); s0 += __shfl_xor(s0, 32);
    s1 += __shfl_xor(s1, 16); s1 += __shfl_xor(s1, 32);
    s2 += __shfl_xor(s2, 16); s2 += __shfl_xor(s2, 32);
    s3 += __shfl_xor(s3, 16); s3 += __shfl_xor(s3, 32);
    int o4 = row * 16 + p;                  // float4 / ushort4 index
    if (LAST) {
        if (g == 0) {
            float4 a = acc[o4];
            out[o4] = make_float4((a.x + s0) * 0.25f, (a.y + s1) * 0.25f,
                                  (a.z + s2) * 0.25f, (a.w + s3) * 0.25f);
        }
    } else {
        if (g == 0) {
            float4 a = acc[o4];
            acc[o4] = make_float4(a.x + s0, a.y + s1, a.z + s2, a.w + s3);
        } else if (g == 1) {
            ushort4 h;
            h.x = f2bf(s0); h.y = f2bf(s1); h.z = f2bf(s2); h.w = f2bf(s3);
            xout[o4] = h;
        }
    }
}

extern "C" void kernel_launch(void* const* d_in, const int* in_sizes, int n_in,
                              void* d_out, int out_size, void* d_ws, size_t ws_size,
                              hipStream_t stream) {
    const int*   rows = (const int*)d_in[0];
    const int*   cols = (const int*)d_in[1];
    const float* vals = (const float*)d_in[2];
    float* out = (float*)d_out;

    char* w = (char*)d_ws;
    size_t p = 0;
#define WALLOC(var, type, count) \
    type* var = (type*)(w + p); p += (((size_t)(count) * sizeof(type)) + 255) & ~(size_t)255;
    WALLOC(bucketcur, int, NBUCK)
    WALLOC(gtotal,    int, 64)
    WALLOC(off,       int, NN)
    WALLOC(cnt,       int, NN)
    // overlay region: subbuf is dead after k_csr; xa/xb/acc reuse its space
    size_t regA = p;
    int2* subbuf = (int2*)(w + regA);               // 2360*5632*8 = 106.3 MB
    size_t subbuf_sz = ((size_t)NBUCK * CAPB * sizeof(int2) + 255) & ~(size_t)255;
    u16*   xa  = (u16*)(w + regA);                  // 19.3 MB
    u16*   xb  = (u16*)(w + regA + (size_t)NN * D * sizeof(u16));
    float* acc = (float*)(w + regA + 2 * (size_t)NN * D * sizeof(u16));  // 38.6 MB
    p = regA + subbuf_sz;
    WALLOC(cicv, int2, (size_t)NE + 16)             // +16 pad: spmm tail (clamped)
#undef WALLOC
    (void)p; (void)ws_size; (void)in_sizes; (void)n_in; (void)out_size;

    hipMemsetAsync(bucketcur, 0, (size_t)NBUCK * sizeof(int), stream);
    hipMemsetAsync(gtotal, 0, sizeof(int), stream);

    k_bin<<<BINB, BINT, 0, stream>>>(rows, cols, vals, bucketcur, subbuf);
    k_csr<<<NBUCK, 256, 0, stream>>>(bucketcur, subbuf, off, cnt, gtotal, cicv);
    k_init<<<(NN * D / 4 + 255) / 256, 256, 0, stream>>>(
        (const float4*)d_in[3], (const float4*)d_in[4],
        (const float4*)d_in[5], (ushort4*)xa, (float4*)acc);

    int spmm_blocks = NN / 4;   // 4 waves (rows) per 256-thread block; NN%4==0
    k_spmm<0><<<spmm_blocks, 256, 0, stream>>>(off, cnt, cicv, xa, (ushort4*)xb,
                                               (float4*)acc, (float4*)out);
    k_spmm<0><<<spmm_blocks, 256, 0, stream>>>(off, cnt, cicv, xb, (ushort4*)xa,
                                               (float4*)acc, (float4*)out);
    k_spmm<1><<<spmm_blocks, 256, 0, stream>>>(off, cnt, cicv, xa, (ushort4*)xb,
                                               (float4*)acc, (float4*)out);

    // echo user_emb / item_emb (fp32)
    hipMemcpyAsync(out + (size_t)NN * D, d_in[3], (size_t)NU * D * sizeof(float),
                   hipMemcpyDeviceToDevice, stream);
    hipMemcpyAsync(out + (size_t)NN * D + (size_t)NU * D, d_in[4],
                   (size_t)NI * D * sizeof(float), hipMemcpyDeviceToDevice, stream);
}

// Round 10
// 989.589 us; speedup vs baseline: 1.8236x; 1.0087x over previous
//
#include <hip/hip_runtime.h>
#include <hip/hip_bf16.h>
#include <stdint.h>

#define NU 100000
#define NI 50000
#define NB 1000
#define NN 151000      // total nodes
#define D  64
#define NE 10000000

#define BSH   6                   // 64 rows per bucket
#define BROWS 64
#define NBUCK 2360                // ceil(NN / 64)
#define CAPB  5632                // bucket capacity (mean 4238, sigma ~65 -> +21 sigma)
#define BINB  512                 // k_bin blocks (2 per CU)
#define BINT  1024                // k_bin threads per block

typedef unsigned short u16;
typedef unsigned int   u32;

__device__ __forceinline__ u16 f2bf(float f) {
    union { float f; u32 i; } c; c.f = f;
    u32 lsb = (c.i >> 16) & 1;          // round-to-nearest-even bf16
    c.i += 0x7fffu + lsb;
    return (u16)(c.i >> 16);
}

// ---- phase 1: block-local counting sort into bucket regions.
// One global atomic per (block,bucket); stores are contiguous runs.
__global__ __launch_bounds__(BINT) void k_bin(
    const int* __restrict__ rows, const int* __restrict__ cols,
    const float* __restrict__ vals,
    int* __restrict__ bucketcur, int2* __restrict__ subbuf) {
    __shared__ int hcnt[NBUCK];   // 9.4 KB
    __shared__ int hcur[NBUCK];   // 9.4 KB
    int b = blockIdx.x, tid = threadIdx.x;
    long e0 = (long)b * NE / BINB;
    long e1 = (long)(b + 1) * NE / BINB;
    for (int j = tid; j < NBUCK; j += BINT) hcnt[j] = 0;
    __syncthreads();
    for (long i = e0 + tid; i < e1; i += BINT)
        atomicAdd(&hcnt[rows[i] >> BSH], 1);            // LDS atomic
    __syncthreads();
    for (int j = tid; j < NBUCK; j += BINT) {
        int c = hcnt[j];
        hcur[j] = c ? atomicAdd(&bucketcur[j], c) : 0;  // chunk reservation
    }
    __syncthreads();
    for (long i = e0 + tid; i < e1; i += BINT) {
        int r  = rows[i];
        int bk = r >> BSH;
        int pos = atomicAdd(&hcur[bk], 1);              // LDS atomic
        if (pos < CAPB)
            subbuf[(size_t)bk * CAPB + pos] =
                make_int2(((r & (BROWS - 1)) << 18) | cols[i], __float_as_int(vals[i]));
    }
}

// ---- phase 2: per-bucket CSR build entirely in LDS; sequential global writes ----
__global__ __launch_bounds__(256) void k_csr(
    const int* __restrict__ bucketcur, const int2* __restrict__ subbuf,
    int* __restrict__ off, int* __restrict__ cnt, int* __restrict__ gtotal,
    int2* __restrict__ cicv) {
    __shared__ int rcnt[BROWS], rexc[BROWS], lcur[BROWS];
    __shared__ int sbase;
    __shared__ int2 sbuf[CAPB];   // 45 KB
    int b = blockIdx.x, tid = threadIdx.x;
    int T = bucketcur[b]; if (T > CAPB) T = CAPB;
    if (tid < BROWS) rcnt[tid] = 0;
    __syncthreads();
    const int2* src = subbuf + (size_t)b * CAPB;
    for (int j = tid; j < T; j += 256)
        atomicAdd(&rcnt[(u32)src[j].x >> 18], 1);
    __syncthreads();
    if (tid < 64) {
        int v = rcnt[tid], x = v;
        for (int d = 1; d < 64; d <<= 1) {
            int t = __shfl_up(x, d);
            if (tid >= d) x += t;
        }
        rexc[tid] = x - v;
        if (tid == 63) sbase = atomicAdd(gtotal, x);   // disjoint segments, order-free
    }
    __syncthreads();
    int base = sbase;
    if (tid < BROWS) {
        int r = b * BROWS + tid;
        if (r < NN) { off[r] = base + rexc[tid]; cnt[r] = rcnt[tid]; }
        lcur[tid] = rexc[tid];
    }
    __syncthreads();
    for (int j = tid; j < T; j += 256) {
        int2 rec = src[j];
        int rl = (u32)rec.x >> 18;
        int dst = atomicAdd(&lcur[rl], 1);
        sbuf[dst] = make_int2(rec.x & 0x3FFFF, rec.y);
    }
    __syncthreads();
    for (int j = tid; j < T; j += 256)     // purely sequential coalesced stores
        cicv[base + j] = sbuf[j];
}

// ---- x0 = concat(embeddings) -> bf16 xa; acc = fp32 copy ----
__global__ void k_init(const float4* __restrict__ ue, const float4* __restrict__ ie,
                       const float4* __restrict__ be, ushort4* __restrict__ xa,
                       float4* __restrict__ acc) {
    int i4 = blockIdx.x * blockDim.x + threadIdx.x;   // unit of 4 floats
    if (i4 >= NN * D / 4) return;
    float4 v;
    if (i4 < NU * D / 4)             v = ue[i4];
    else if (i4 < (NU + NI) * D / 4) v = ie[i4 - NU * D / 4];
    else                             v = be[i4 - (NU + NI) * D / 4];
    acc[i4] = v;
    ushort4 h;
    h.x = f2bf(v.x); h.y = f2bf(v.y); h.z = f2bf(v.z); h.w = f2bf(v.w);
    xa[i4] = h;
}

__device__ __forceinline__ void acc8(float f, uint4 h, float* s) {
    union { u32 i; float v; } t;
    t.i = h.x << 16;         s[0] += f * t.v;
    t.i = h.x & 0xffff0000u; s[1] += f * t.v;
    t.i = h.y << 16;         s[2] += f * t.v;
    t.i = h.y & 0xffff0000u; s[3] += f * t.v;
    t.i = h.z << 16;         s[4] += f * t.v;
    t.i = h.z & 0xffff0000u; s[5] += f * t.v;
    t.i = h.w << 16;         s[6] += f * t.v;
    t.i = h.w & 0xffff0000u; s[7] += f * t.v;
}

// ---- SpMM: one wave per row; 8 edges per gather instr, 32 edges/iter.
// lane = (q,p): q=lane>>3 edge slot 0..7, p=lane&7 dim octet (16B/lane loads).
template<int LAST>
__global__ __launch_bounds__(256) void k_spmm(
    const int* __restrict__ off, const int* __restrict__ cnt,
    const int2* __restrict__ cicv,
    const u16* __restrict__ xin, uint4* __restrict__ xout,
    float4* __restrict__ acc, float4* __restrict__ out) {
    int gid  = blockIdx.x * blockDim.x + threadIdx.x;
    int row  = gid >> 6;
    int lane = threadIdx.x & 63;
    if (row >= NN) return;
    int base = __builtin_amdgcn_readfirstlane(off[row]);
    int deg  = __builtin_amdgcn_readfirstlane(cnt[row]);
    int q = lane >> 3;
    int p = lane & 7;
    float s[8] = {0.f, 0.f, 0.f, 0.f, 0.f, 0.f, 0.f, 0.f};
    for (int e = 0; e < deg; e += 32) {
        int2 r0 = cicv[base + e + q];           // 8-lane broadcast groups
        int2 r1 = cicv[base + e + 8 + q];
        int2 r2 = cicv[base + e + 16 + q];
        int2 r3 = cicv[base + e + 24 + q];
        bool ok0 = (e + q)      < deg;
        bool ok1 = (e + 8 + q)  < deg;
        bool ok2 = (e + 16 + q) < deg;
        bool ok3 = (e + 24 + q) < deg;
        int c0 = ok0 ? r0.x : 0;  float f0 = ok0 ? __int_as_float(r0.y) : 0.f;
        int c1 = ok1 ? r1.x : 0;  float f1 = ok1 ? __int_as_float(r1.y) : 0.f;
        int c2 = ok2 ? r2.x : 0;  float f2 = ok2 ? __int_as_float(r2.y) : 0.f;
        int c3 = ok3 ? r3.x : 0;  float f3 = ok3 ? __int_as_float(r3.y) : 0.f;
        uint4 h0 = *(const uint4*)(xin + (size_t)c0 * D + p * 8);   // 8 rows x 128B
        uint4 h1 = *(const uint4*)(xin + (size_t)c1 * D + p * 8);
        uint4 h2 = *(const uint4*)(xin + (size_t)c2 * D + p * 8);
        uint4 h3 = *(const uint4*)(xin + (size_t)c3 * D + p * 8);
        acc8(f0, h0, s);
        acc8(f1, h1, s);
        acc8(f2, h2, s);
        acc8(f3, h3, s);
    }
#pragma unroll
    for (int k = 0; k < 8; ++k) {
        s[k] += __shfl_xor(s[k], 8);
        s[k] += __shfl_xor(s[k], 16);
        s[k] += __shfl_xor(s[k], 32);
    }
    int o16 = row * 16 + p * 2;                 // float4 index (2 per lane)
    if (LAST) {
        if (q == 0) {
            float4 a0 = acc[o16], a1 = acc[o16 + 1];
            out[o16]     = make_float4((a0.x + s[0]) * 0.25f, (a0.y + s[1]) * 0.25f,
                                       (a0.z + s[2]) * 0.25f, (a0.w + s[3]) * 0.25f);
            out[o16 + 1] = make_float4((a1.x + s[4]) * 0.25f, (a1.y + s[5]) * 0.25f,
                                       (a1.z + s[6]) * 0.25f, (a1.w + s[7]) * 0.25f);
        }
    } else {
        if (q == 0) {
            float4 a0 = acc[o16], a1 = acc[o16 + 1];
            acc[o16]     = make_float4(a0.x + s[0], a0.y + s[1], a0.z + s[2], a0.w + s[3]);
            acc[o16 + 1] = make_float4(a1.x + s[4], a1.y + s[5], a1.z + s[6], a1.w + s[7]);
        } else if (q == 1) {
            uint4 hh;
            hh.x = (u32)f2bf(s[0]) | ((u32)f2bf(s[1]) << 16);
            hh.y = (u32)f2bf(s[2]) | ((u32)f2bf(s[3]) << 16);
            hh.z = (u32)f2bf(s[4]) | ((u32)f2bf(s[5]) << 16);
            hh.w = (u32)f2bf(s[6]) | ((u32)f2bf(s[7]) << 16);
            xout[row * 8 + p] = hh;
        }
    }
}

extern "C" void kernel_launch(void* const* d_in, const int* in_sizes, int n_in,
                              void* d_out, int out_size, void* d_ws, size_t ws_size,
                              hipStream_t stream) {
    const int*   rows = (const int*)d_in[0];
    const int*   cols = (const int*)d_in[1];
    const float* vals = (const float*)d_in[2];
    float* out = (float*)d_out;

    char* w = (char*)d_ws;
    size_t p = 0;
#define WALLOC(var, type, count) \
    type* var = (type*)(w + p); p += (((size_t)(count) * sizeof(type)) + 255) & ~(size_t)255;
    WALLOC(bucketcur, int, NBUCK)
    WALLOC(gtotal,    int, 64)
    WALLOC(off,       int, NN)
    WALLOC(cnt,       int, NN)
    // overlay region: subbuf is dead after k_csr; xa/xb/acc reuse its space
    size_t regA = p;
    int2* subbuf = (int2*)(w + regA);               // 2360*5632*8 = 106.3 MB
    size_t subbuf_sz = ((size_t)NBUCK * CAPB * sizeof(int2) + 255) & ~(size_t)255;
    u16*   xa  = (u16*)(w + regA);                  // 19.3 MB
    u16*   xb  = (u16*)(w + regA + (size_t)NN * D * sizeof(u16));
    float* acc = (float*)(w + regA + 2 * (size_t)NN * D * sizeof(u16));  // 38.6 MB
    p = regA + subbuf_sz;
    WALLOC(cicv, int2, (size_t)NE + 32)             // +32 pad: spmm tail (masked)
#undef WALLOC
    (void)p; (void)ws_size; (void)in_sizes; (void)n_in; (void)out_size;

    hipMemsetAsync(bucketcur, 0, (size_t)NBUCK * sizeof(int), stream);
    hipMemsetAsync(gtotal, 0, sizeof(int), stream);

    k_bin<<<BINB, BINT, 0, stream>>>(rows, cols, vals, bucketcur, subbuf);
    k_csr<<<NBUCK, 256, 0, stream>>>(bucketcur, subbuf, off, cnt, gtotal, cicv);
    k_init<<<(NN * D / 4 + 255) / 256, 256, 0, stream>>>(
        (const float4*)d_in[3], (const float4*)d_in[4],
        (const float4*)d_in[5], (ushort4*)xa, (float4*)acc);

    int spmm_blocks = NN / 4;   // 4 waves (rows) per 256-thread block; NN%4==0
    k_spmm<0><<<spmm_blocks, 256, 0, stream>>>(off, cnt, cicv, xa, (uint4*)xb,
                                               (float4*)acc, (float4*)out);
    k_spmm<0><<<spmm_blocks, 256, 0, stream>>>(off, cnt, cicv, xb, (uint4*)xa,
                                               (float4*)acc, (float4*)out);
    k_spmm<1><<<spmm_blocks, 256, 0, stream>>>(off, cnt, cicv, xa, (uint4*)xb,
                                               (float4*)acc, (float4*)out);

    // echo user_emb / item_emb (fp32)
    hipMemcpyAsync(out + (size_t)NN * D, d_in[3], (size_t)NU * D * sizeof(float),
                   hipMemcpyDeviceToDevice, stream);
    hipMemcpyAsync(out + (size_t)NN * D + (size_t)NU * D, d_in[4],
                   (size_t)NI * D * sizeof(float), hipMemcpyDeviceToDevice, stream);
}